// Round 6
// baseline (309.307 us; speedup 1.0000x reference)
//
#include <hip/hip_runtime.h>
#include <stdint.h>

#define N_TOK 64
#define K_DIM 4096
#define N_OUT 11008
#define LUT_N 256
#define DQ_ITERS 8
#define DQ_BLOCKS 2752  // 2752*8*256 threads-iters * 8 idx = 45,088,768 ✓

typedef __attribute__((ext_vector_type(4))) float  floatx4;
typedef __attribute__((ext_vector_type(8))) __bf16 bf16x8;

__device__ __forceinline__ unsigned bf16_rne(float f) {
  unsigned u = __builtin_bit_cast(unsigned, f);
  return (u + 0x7fffu + ((u >> 16) & 1u)) >> 16;  // round-nearest-even to bf16
}

// ---- pass 1a: pack x (fp32 [64][4096]) into A-fragment-ordered bf16 ----
// chunk c = kstep*4 + tt, kstep in [0,128); lane (q=lane>>4, m15=lane&15)
// holds 8 bf16: x[(tt*16+m15)*4096 + kstep*32 + q*8 + j]
__global__ __launch_bounds__(256) void xpack_kernel(const float* __restrict__ x,
                                                    uint32_t* __restrict__ xp) {
  const int t = blockIdx.x * 256 + threadIdx.x;  // [0, 32768)
  const int lane = t & 63, c = t >> 6;
  const int m15 = lane & 15, q = lane >> 4;
  const int tt = c & 3, kstep = c >> 2;
  const int src = (tt * 16 + m15) * K_DIM + kstep * 32 + q * 8;
  float4 a = *(const float4*)(x + src);
  float4 b = *(const float4*)(x + src + 4);
  uint4 o;
  o.x = bf16_rne(a.x) | (bf16_rne(a.y) << 16);
  o.y = bf16_rne(a.z) | (bf16_rne(a.w) << 16);
  o.z = bf16_rne(b.x) | (bf16_rne(b.y) << 16);
  o.w = bf16_rne(b.z) | (bf16_rne(b.w) << 16);
  *(uint4*)(xp + (size_t)t * 4) = o;
}

// ---- pass 1b: streaming dequant, GRID-STRIDE + depth-2 register pipeline ----
// Thread-iteration t: o = t>>9, kc = t&511; reads gi[t*8 .. t*8+7] (32 B
// contiguous; wave = 2 KB burst; block sweeps 64 KB), writes B-frag unit
// (to=o>>4, tk=kc>>2) at 16-B unit (o&15)*4 + (kc&3).
// Loads for iter j+1 are issued BEFORE consuming iter j => steady-state
// in-flight ~2 KB/wave x 32 waves/CU; LUT init amortized over 8 iters.
__global__ __launch_bounds__(256, 8) void dequant_kernel(const int* __restrict__ gi,
                                                         const float* __restrict__ lut,
                                                         uint4* __restrict__ wt) {
  __shared__ uint32_t lut_lds[LUT_N * 16];  // 16 bank-strided copies, bf16 in low16
  {
    unsigned hb = bf16_rne(lut[threadIdx.x]);
#pragma unroll
    for (int c = 0; c < 16; ++c) lut_lds[threadIdx.x * 16 + c] = hb;
  }
  __syncthreads();

  const int slot = threadIdx.x & 15;
  const size_t t0 = (size_t)blockIdx.x * (DQ_ITERS * 256) + threadIdx.x;
  const int4* gp = (const int4*)gi;  // thread-iter t reads gp[2t], gp[2t+1]

  int4 pa[2], pb[2];
  pa[0] = gp[t0 * 2];
  pb[0] = gp[t0 * 2 + 1];

#pragma unroll
  for (int j = 0; j < DQ_ITERS; ++j) {
    const int p = j & 1;
    const int4 a = pa[p], b = pb[p];
    if (j + 1 < DQ_ITERS) {  // prefetch iter j+1 (issued before any use of a,b)
      const size_t tn = t0 + (size_t)(j + 1) * 256;
      pa[p ^ 1] = gp[tn * 2];
      pb[p ^ 1] = gp[tn * 2 + 1];
    }

    unsigned g0 = lut_lds[a.x * 16 + slot];
    unsigned g1 = lut_lds[a.y * 16 + slot];
    unsigned g2 = lut_lds[a.z * 16 + slot];
    unsigned g3 = lut_lds[a.w * 16 + slot];
    unsigned g4 = lut_lds[b.x * 16 + slot];
    unsigned g5 = lut_lds[b.y * 16 + slot];
    unsigned g6 = lut_lds[b.z * 16 + slot];
    unsigned g7 = lut_lds[b.w * 16 + slot];
    uint4 u;
    u.x = __builtin_amdgcn_perm(g1, g0, 0x05040100u);  // [bf16(k0)|bf16(k1)<<16]
    u.y = __builtin_amdgcn_perm(g3, g2, 0x05040100u);
    u.z = __builtin_amdgcn_perm(g5, g4, 0x05040100u);
    u.w = __builtin_amdgcn_perm(g7, g6, 0x05040100u);

    const size_t t = t0 + (size_t)j * 256;
    const int o = (int)(t >> 9), kc = (int)(t & 511);
    wt[((size_t)(o >> 4) * 128 + (kc >> 2)) * 64 + (o & 15) * 4 + (kc & 3)] = u;
  }
}

// ---- pass 2: dense bf16 GEMM, fragment-direct loads, no LDS in K-loop ----
// block: 16 output features (= one tile-row of wt), 4 waves; wave w owns
// kstep in [w*32, w*32+32). Both streams register-pipelined depth 4.
// B reads: 1 KB contiguous per wave-instr; wt is L3-warm from pass 1b.
// MFMA 16x16x32 bf16: A[m=lane&15][k=q*8+j], B[k=q*8+j][n=lane&15];
// C/D: row(token)=q*4+reg, col(feature)=lane&15.
__global__ __launch_bounds__(256, 3) void gemm_kernel(
    const uint4* __restrict__ wt, const uint32_t* __restrict__ xp,
    const float* __restrict__ scale, float* __restrict__ out) {
  __shared__ floatx4 red[4][4][64];  // 16 KB cross-wave reduction buffer

  const int tid = threadIdx.x;
  const int w = tid >> 6, lane = tid & 63;
  const int m15 = lane & 15, q = lane >> 4;

  const uint4* bp = wt + (size_t)blockIdx.x * 128 * 64 + m15 * 4 + q;
  const uint4* ap = (const uint4*)xp + lane;

  floatx4 acc[4];
#pragma unroll
  for (int tt = 0; tt < 4; ++tt) acc[tt] = (floatx4){0.f, 0.f, 0.f, 0.f};

  uint4 bb[4];     // B pipeline, depth 4
  uint4 ab[4][4];  // A pipeline, depth 4 x 4 token-tiles
#pragma unroll
  for (int p = 0; p < 4; ++p) {
    bb[p] = bp[(size_t)(w * 32 + p) * 64];
#pragma unroll
    for (int tt = 0; tt < 4; ++tt)
      ab[p][tt] = ap[(size_t)((w * 32 + p) * 4 + tt) * 64];
  }

#pragma unroll 4
  for (int st = 0; st < 32; ++st) {
    const int p = st & 3;
    const uint4 bv = bb[p];
    uint4 a0 = ab[p][0], a1 = ab[p][1], a2 = ab[p][2], a3 = ab[p][3];
    if (st < 28) {  // prefetch step st+4 before any dependent use
      bb[p] = bp[(size_t)(w * 32 + st + 4) * 64];
#pragma unroll
      for (int tt = 0; tt < 4; ++tt)
        ab[p][tt] = ap[(size_t)((w * 32 + st + 4) * 4 + tt) * 64];
    }

    const bf16x8 bfrag = __builtin_bit_cast(bf16x8, bv);
    acc[0] = __builtin_amdgcn_mfma_f32_16x16x32_bf16(
        __builtin_bit_cast(bf16x8, a0), bfrag, acc[0], 0, 0, 0);
    acc[1] = __builtin_amdgcn_mfma_f32_16x16x32_bf16(
        __builtin_bit_cast(bf16x8, a1), bfrag, acc[1], 0, 0, 0);
    acc[2] = __builtin_amdgcn_mfma_f32_16x16x32_bf16(
        __builtin_bit_cast(bf16x8, a2), bfrag, acc[2], 0, 0, 0);
    acc[3] = __builtin_amdgcn_mfma_f32_16x16x32_bf16(
        __builtin_bit_cast(bf16x8, a3), bfrag, acc[3], 0, 0, 0);
  }

  // ---- cross-wave K reduction + scale + store ----
  __syncthreads();
#pragma unroll
  for (int tt = 0; tt < 4; ++tt) red[w][tt][lane] = acc[tt];
  __syncthreads();
  {
    floatx4 r = red[0][w][lane];
    r += red[1][w][lane];
    r += red[2][w][lane];
    r += red[3][w][lane];
    const float sc = scale[blockIdx.x * 16 + m15];
    r *= sc;
#pragma unroll
    for (int i = 0; i < 4; ++i)
      out[(size_t)(16 * w + q * 4 + i) * N_OUT + blockIdx.x * 16 + m15] = r[i];
  }
}

extern "C" void kernel_launch(void* const* d_in, const int* in_sizes, int n_in,
                              void* d_out, int out_size, void* d_ws, size_t ws_size,
                              hipStream_t stream) {
  const float* x   = (const float*)d_in[0];
  const int*   gi  = (const int*)d_in[1];
  const float* lut = (const float*)d_in[2];
  const float* sc  = (const float*)d_in[3];
  float*       out = (float*)d_out;

  // ws layout: [0, 512 KB) packed-A bf16 ; [1 MB, 1 MB + 90.2 MB) tiled W bf16
  uint32_t* xp = (uint32_t*)d_ws;
  uint4*    wt = (uint4*)((uint8_t*)d_ws + (1u << 20));

  xpack_kernel<<<(N_TOK * K_DIM / 8) / 256, 256, 0, stream>>>(x, xp);
  dequant_kernel<<<DQ_BLOCKS, 256, 0, stream>>>(gi, lut, wt);
  gemm_kernel<<<N_OUT / 16, 256, 0, stream>>>(wt, xp, sc, out);
}

// Round 7
// 303.731 us; speedup vs baseline: 1.0184x; 1.0184x over previous
//
#include <hip/hip_runtime.h>
#include <stdint.h>

#define N_TOK 64
#define K_DIM 4096
#define N_OUT 11008
#define LUT_N 256

typedef __attribute__((ext_vector_type(4))) float  floatx4;
typedef __attribute__((ext_vector_type(8))) __bf16 bf16x8;

__device__ __forceinline__ unsigned bf16_rne(float f) {
  unsigned u = __builtin_bit_cast(unsigned, f);
  return (u + 0x7fffu + ((u >> 16) & 1u)) >> 16;  // round-nearest-even to bf16
}

// ---- pass 1a: pack x (fp32 [64][4096]) into A-fragment-ordered bf16 ----
// chunk c = kstep*4 + tt, kstep in [0,128); lane (q=lane>>4, m15=lane&15)
// holds 8 bf16: x[(tt*16+m15)*4096 + kstep*32 + q*8 + j]
__global__ __launch_bounds__(256) void xpack_kernel(const float* __restrict__ x,
                                                    uint32_t* __restrict__ xp) {
  const int t = blockIdx.x * 256 + threadIdx.x;  // [0, 32768)
  const int lane = t & 63, c = t >> 6;
  const int m15 = lane & 15, q = lane >> 4;
  const int tt = c & 3, kstep = c >> 2;
  const int src = (tt * 16 + m15) * K_DIM + kstep * 32 + q * 8;
  float4 a = *(const float4*)(x + src);
  float4 b = *(const float4*)(x + src + 4);
  uint4 o;
  o.x = bf16_rne(a.x) | (bf16_rne(a.y) << 16);
  o.y = bf16_rne(a.z) | (bf16_rne(a.w) << 16);
  o.z = bf16_rne(b.x) | (bf16_rne(b.y) << 16);
  o.w = bf16_rne(b.z) | (bf16_rne(b.w) << 16);
  *(uint4*)(xp + (size_t)t * 4) = o;
}

// ---- pass 1b: streaming dequant, FULLY SEQUENTIAL both sides ----
// Thread t: reads gi[8t..8t+7] (32 B contiguous), writes wt[t] (16 B
// contiguous across threads => wave writes 1 KB = 8 full 128-B lines; no
// partial-line RFO). wt = row-major bf16 W: wt[o*512 + kc] holds
// W[o][kc*8 .. kc*8+7].
__global__ __launch_bounds__(256) void dequant_kernel(const int* __restrict__ gi,
                                                      const float* __restrict__ lut,
                                                      uint4* __restrict__ wt) {
  __shared__ uint32_t lut_lds[LUT_N * 16];  // 16 bank-strided copies, bf16 in low16
  {
    unsigned hb = bf16_rne(lut[threadIdx.x]);
#pragma unroll
    for (int c = 0; c < 16; ++c) lut_lds[threadIdx.x * 16 + c] = hb;
  }
  __syncthreads();

  const int slot = threadIdx.x & 15;
  const size_t t = (size_t)blockIdx.x * 256 + threadIdx.x;  // [0, 5636096)
  const int4* p = (const int4*)gi + t * 2;
  const int4 a = p[0], b = p[1];

  unsigned g0 = lut_lds[a.x * 16 + slot];
  unsigned g1 = lut_lds[a.y * 16 + slot];
  unsigned g2 = lut_lds[a.z * 16 + slot];
  unsigned g3 = lut_lds[a.w * 16 + slot];
  unsigned g4 = lut_lds[b.x * 16 + slot];
  unsigned g5 = lut_lds[b.y * 16 + slot];
  unsigned g6 = lut_lds[b.z * 16 + slot];
  unsigned g7 = lut_lds[b.w * 16 + slot];
  uint4 u;
  u.x = __builtin_amdgcn_perm(g1, g0, 0x05040100u);  // [bf16(k0)|bf16(k1)<<16]
  u.y = __builtin_amdgcn_perm(g3, g2, 0x05040100u);
  u.z = __builtin_amdgcn_perm(g5, g4, 0x05040100u);
  u.w = __builtin_amdgcn_perm(g7, g6, 0x05040100u);

  wt[t] = u;
}

// ---- pass 2: dense bf16 GEMM over row-major W, fragment-direct loads ----
// block: 16 output features, 4 waves; wave w owns kstep in [w*32, w*32+32).
// B-frag for lane (n=m15, q): W[n][kstep*32+q*8 .. +7] = wt[(blk*16+m15)*512
// + kstep*4 + q] — 16x64-B reads/wave-instr at 8-KB stride, served by
// L2/L3 (wt is LLC-warm from pass 1b; kstep,kstep+1 share each 128-B line).
// A from L2-resident xp. Both streams register-pipelined depth 4.
// MFMA 16x16x32 bf16: A[m=lane&15][k=q*8+j], B[k=q*8+j][n=lane&15];
// C/D: row(token)=q*4+reg, col(feature)=lane&15.
__global__ __launch_bounds__(256, 3) void gemm_kernel(
    const uint4* __restrict__ wt, const uint32_t* __restrict__ xp,
    const float* __restrict__ scale, float* __restrict__ out) {
  __shared__ floatx4 red[4][4][64];  // 16 KB cross-wave reduction buffer

  const int tid = threadIdx.x;
  const int w = tid >> 6, lane = tid & 63;
  const int m15 = lane & 15, q = lane >> 4;

  const uint4* bp = wt + (size_t)(blockIdx.x * 16 + m15) * 512 + q;
  const uint4* ap = (const uint4*)xp + lane;

  floatx4 acc[4];
#pragma unroll
  for (int tt = 0; tt < 4; ++tt) acc[tt] = (floatx4){0.f, 0.f, 0.f, 0.f};

  uint4 bb[4];     // B pipeline, depth 4
  uint4 ab[4][4];  // A pipeline, depth 4 x 4 token-tiles
#pragma unroll
  for (int p = 0; p < 4; ++p) {
    bb[p] = bp[(w * 32 + p) * 4];
#pragma unroll
    for (int tt = 0; tt < 4; ++tt)
      ab[p][tt] = ap[(size_t)((w * 32 + p) * 4 + tt) * 64];
  }

#pragma unroll 4
  for (int st = 0; st < 32; ++st) {
    const int p = st & 3;
    const uint4 bv = bb[p];
    uint4 a0 = ab[p][0], a1 = ab[p][1], a2 = ab[p][2], a3 = ab[p][3];
    if (st < 28) {  // prefetch step st+4 before any dependent use
      bb[p] = bp[(w * 32 + st + 4) * 4];
#pragma unroll
      for (int tt = 0; tt < 4; ++tt)
        ab[p][tt] = ap[(size_t)((w * 32 + st + 4) * 4 + tt) * 64];
    }

    const bf16x8 bfrag = __builtin_bit_cast(bf16x8, bv);
    acc[0] = __builtin_amdgcn_mfma_f32_16x16x32_bf16(
        __builtin_bit_cast(bf16x8, a0), bfrag, acc[0], 0, 0, 0);
    acc[1] = __builtin_amdgcn_mfma_f32_16x16x32_bf16(
        __builtin_bit_cast(bf16x8, a1), bfrag, acc[1], 0, 0, 0);
    acc[2] = __builtin_amdgcn_mfma_f32_16x16x32_bf16(
        __builtin_bit_cast(bf16x8, a2), bfrag, acc[2], 0, 0, 0);
    acc[3] = __builtin_amdgcn_mfma_f32_16x16x32_bf16(
        __builtin_bit_cast(bf16x8, a3), bfrag, acc[3], 0, 0, 0);
  }

  // ---- cross-wave K reduction + scale + store ----
  __syncthreads();
#pragma unroll
  for (int tt = 0; tt < 4; ++tt) red[w][tt][lane] = acc[tt];
  __syncthreads();
  {
    floatx4 r = red[0][w][lane];
    r += red[1][w][lane];
    r += red[2][w][lane];
    r += red[3][w][lane];
    const float sc = scale[blockIdx.x * 16 + m15];
    r *= sc;
#pragma unroll
    for (int i = 0; i < 4; ++i)
      out[(size_t)(16 * w + q * 4 + i) * N_OUT + blockIdx.x * 16 + m15] = r[i];
  }
}

extern "C" void kernel_launch(void* const* d_in, const int* in_sizes, int n_in,
                              void* d_out, int out_size, void* d_ws, size_t ws_size,
                              hipStream_t stream) {
  const float* x   = (const float*)d_in[0];
  const int*   gi  = (const int*)d_in[1];
  const float* lut = (const float*)d_in[2];
  const float* sc  = (const float*)d_in[3];
  float*       out = (float*)d_out;

  // ws layout: [0, 512 KB) packed-A bf16 ; [1 MB, 1 MB + 90.2 MB) row-major W bf16
  uint32_t* xp = (uint32_t*)d_ws;
  uint4*    wt = (uint4*)((uint8_t*)d_ws + (1u << 20));

  xpack_kernel<<<(N_TOK * K_DIM / 8) / 256, 256, 0, stream>>>(x, xp);
  dequant_kernel<<<(N_OUT * K_DIM / 8) / 256, 256, 0, stream>>>(gi, lut, wt);
  gemm_kernel<<<N_OUT / 16, 256, 0, stream>>>(wt, xp, sc, out);
}

// Round 8
// 299.762 us; speedup vs baseline: 1.0318x; 1.0132x over previous
//
#include <hip/hip_runtime.h>
#include <stdint.h>

#define N_TOK 64
#define K_DIM 4096
#define N_OUT 11008
#define LUT_N 256

typedef __attribute__((ext_vector_type(4))) float  floatx4;
typedef __attribute__((ext_vector_type(8))) __bf16 bf16x8;

__device__ __forceinline__ unsigned bf16_rne(float f) {
  unsigned u = __builtin_bit_cast(unsigned, f);
  return (u + 0x7fffu + ((u >> 16) & 1u)) >> 16;  // round-nearest-even to bf16
}

// ---- pass 1a: pack x (fp32 [64][4096]) into A-fragment-ordered bf16 ----
// chunk c = kstep*4 + tt, kstep in [0,128); lane (q=lane>>4, m15=lane&15)
// holds 8 bf16: x[(tt*16+m15)*4096 + kstep*32 + q*8 + j]
__global__ __launch_bounds__(256) void xpack_kernel(const float* __restrict__ x,
                                                    uint32_t* __restrict__ xp) {
  const int t = blockIdx.x * 256 + threadIdx.x;  // [0, 32768)
  const int lane = t & 63, c = t >> 6;
  const int m15 = lane & 15, q = lane >> 4;
  const int tt = c & 3, kstep = c >> 2;
  const int src = (tt * 16 + m15) * K_DIM + kstep * 32 + q * 8;
  float4 a = *(const float4*)(x + src);
  float4 b = *(const float4*)(x + src + 4);
  uint4 o;
  o.x = bf16_rne(a.x) | (bf16_rne(a.y) << 16);
  o.y = bf16_rne(a.z) | (bf16_rne(a.w) << 16);
  o.z = bf16_rne(b.x) | (bf16_rne(b.y) << 16);
  o.w = bf16_rne(b.z) | (bf16_rne(b.w) << 16);
  *(uint4*)(xp + (size_t)t * 4) = o;
}

// ---- pass 1b: dequant into B-tile layout, FULL-LINE writes per wave ----
// Wave-task Wv = blk*4+v in [0,44032): to=Wv>>7, p=(Wv&127)>>4, win=Wv&15.
// Lane l: r=(l>>2)&1, a=l>>3, q=l&3 -> row o=to*16+2p+r, kc=win*32+a*4+q.
// Reads: two 1-KB contiguous bursts (rows o0,o0+1), lane-permuted.
// Writes: lanes 8a..8a+7 emit one FULL 128-B line of tile (to, tk=win*8+a)
// at unit (2p+r)*4+q — 8 complete lines/wave, no partial-line RFO.
__global__ __launch_bounds__(256) void dequant_kernel(const int* __restrict__ gi,
                                                      const float* __restrict__ lut,
                                                      uint4* __restrict__ wt) {
  __shared__ uint32_t lut_lds[LUT_N * 16];  // 16 bank-strided copies, bf16 in low16
  {
    unsigned hb = bf16_rne(lut[threadIdx.x]);
#pragma unroll
    for (int c = 0; c < 16; ++c) lut_lds[threadIdx.x * 16 + c] = hb;
  }
  __syncthreads();

  const int slot = threadIdx.x & 15;
  const int l = threadIdx.x & 63, v = threadIdx.x >> 6;
  const int Wv = blockIdx.x * 4 + v;
  const int to = Wv >> 7, rest = Wv & 127;
  const int p = rest >> 4, win = rest & 15;
  const int r = (l >> 2) & 1, aa = l >> 3, q = l & 3;
  const int o = to * 16 + 2 * p + r;
  const int kc = win * 32 + aa * 4 + q;

  const int4* gp = (const int4*)(gi + (size_t)o * K_DIM + kc * 8);
  const int4 a = gp[0], b = gp[1];

  unsigned g0 = lut_lds[a.x * 16 + slot];
  unsigned g1 = lut_lds[a.y * 16 + slot];
  unsigned g2 = lut_lds[a.z * 16 + slot];
  unsigned g3 = lut_lds[a.w * 16 + slot];
  unsigned g4 = lut_lds[b.x * 16 + slot];
  unsigned g5 = lut_lds[b.y * 16 + slot];
  unsigned g6 = lut_lds[b.z * 16 + slot];
  unsigned g7 = lut_lds[b.w * 16 + slot];
  uint4 u;
  u.x = __builtin_amdgcn_perm(g1, g0, 0x05040100u);  // [bf16(k0)|bf16(k1)<<16]
  u.y = __builtin_amdgcn_perm(g3, g2, 0x05040100u);
  u.z = __builtin_amdgcn_perm(g5, g4, 0x05040100u);
  u.w = __builtin_amdgcn_perm(g7, g6, 0x05040100u);

  wt[((size_t)to * 128 + win * 8 + aa) * 64 + (2 * p + r) * 4 + q] = u;
}

// ---- pass 2: dense bf16 GEMM, fragment-direct tile loads (R5 verbatim) ----
// block: 16 output features (= one tile-row of wt), 4 waves; wave w owns
// kstep in [w*32, w*32+32). B reads: 1 KB contiguous per wave-instr; wt is
// LLC-warm from pass 1b. Both streams register-pipelined depth 4.
// MFMA 16x16x32 bf16: A[m=lane&15][k=q*8+j], B[k=q*8+j][n=lane&15];
// C/D: row(token)=q*4+reg, col(feature)=lane&15.
__global__ __launch_bounds__(256, 3) void gemm_kernel(
    const uint4* __restrict__ wt, const uint32_t* __restrict__ xp,
    const float* __restrict__ scale, float* __restrict__ out) {
  __shared__ floatx4 red[4][4][64];  // 16 KB cross-wave reduction buffer

  const int tid = threadIdx.x;
  const int w = tid >> 6, lane = tid & 63;
  const int m15 = lane & 15, q = lane >> 4;

  const uint4* bp = wt + (size_t)blockIdx.x * 128 * 64 + m15 * 4 + q;
  const uint4* ap = (const uint4*)xp + lane;

  floatx4 acc[4];
#pragma unroll
  for (int tt = 0; tt < 4; ++tt) acc[tt] = (floatx4){0.f, 0.f, 0.f, 0.f};

  uint4 bb[4];     // B pipeline, depth 4
  uint4 ab[4][4];  // A pipeline, depth 4 x 4 token-tiles
#pragma unroll
  for (int p = 0; p < 4; ++p) {
    bb[p] = bp[(size_t)(w * 32 + p) * 64];
#pragma unroll
    for (int tt = 0; tt < 4; ++tt)
      ab[p][tt] = ap[(size_t)((w * 32 + p) * 4 + tt) * 64];
  }

#pragma unroll 4
  for (int st = 0; st < 32; ++st) {
    const int p = st & 3;
    const uint4 bv = bb[p];
    uint4 a0 = ab[p][0], a1 = ab[p][1], a2 = ab[p][2], a3 = ab[p][3];
    if (st < 28) {  // prefetch step st+4 before any dependent use
      bb[p] = bp[(size_t)(w * 32 + st + 4) * 64];
#pragma unroll
      for (int tt = 0; tt < 4; ++tt)
        ab[p][tt] = ap[(size_t)((w * 32 + st + 4) * 4 + tt) * 64];
    }

    const bf16x8 bfrag = __builtin_bit_cast(bf16x8, bv);
    acc[0] = __builtin_amdgcn_mfma_f32_16x16x32_bf16(
        __builtin_bit_cast(bf16x8, a0), bfrag, acc[0], 0, 0, 0);
    acc[1] = __builtin_amdgcn_mfma_f32_16x16x32_bf16(
        __builtin_bit_cast(bf16x8, a1), bfrag, acc[1], 0, 0, 0);
    acc[2] = __builtin_amdgcn_mfma_f32_16x16x32_bf16(
        __builtin_bit_cast(bf16x8, a2), bfrag, acc[2], 0, 0, 0);
    acc[3] = __builtin_amdgcn_mfma_f32_16x16x32_bf16(
        __builtin_bit_cast(bf16x8, a3), bfrag, acc[3], 0, 0, 0);
  }

  // ---- cross-wave K reduction + scale + store ----
  __syncthreads();
#pragma unroll
  for (int tt = 0; tt < 4; ++tt) red[w][tt][lane] = acc[tt];
  __syncthreads();
  {
    floatx4 r = red[0][w][lane];
    r += red[1][w][lane];
    r += red[2][w][lane];
    r += red[3][w][lane];
    const float sc = scale[blockIdx.x * 16 + m15];
    r *= sc;
#pragma unroll
    for (int i = 0; i < 4; ++i)
      out[(size_t)(16 * w + q * 4 + i) * N_OUT + blockIdx.x * 16 + m15] = r[i];
  }
}

extern "C" void kernel_launch(void* const* d_in, const int* in_sizes, int n_in,
                              void* d_out, int out_size, void* d_ws, size_t ws_size,
                              hipStream_t stream) {
  const float* x   = (const float*)d_in[0];
  const int*   gi  = (const int*)d_in[1];
  const float* lut = (const float*)d_in[2];
  const float* sc  = (const float*)d_in[3];
  float*       out = (float*)d_out;

  // ws layout: [0, 512 KB) packed-A bf16 ; [1 MB, 1 MB + 90.2 MB) tiled W bf16
  uint32_t* xp = (uint32_t*)d_ws;
  uint4*    wt = (uint4*)((uint8_t*)d_ws + (1u << 20));

  xpack_kernel<<<(N_TOK * K_DIM / 8) / 256, 256, 0, stream>>>(x, xp);
  dequant_kernel<<<(N_OUT * K_DIM / 8) / 256, 256, 0, stream>>>(gi, lut, wt);
  gemm_kernel<<<N_OUT / 16, 256, 0, stream>>>(wt, xp, sc, out);
}